// Round 16
// baseline (87.563 us; speedup 1.0000x reference)
//
#include <hip/hip_runtime.h>
#include <math.h>

#define VOCAB 21128
#define DD 768
#define SS 50
#define TT 5
#define BB 512
#define EE 128
#define CC 10
#define V20 (VOCAB * 20)
#define NG 2560   // utterance graphs; resp graphs are G in [NG, NG+512)
#define NALL 3072 // NG + BB

// ---------------- kernel 0: attG[s][p] = att[p][s], rows padded to 52 ----------------
__global__ void k_prep(const float* __restrict__ att, float* __restrict__ attG) {
    int i = blockIdx.x * 64 + threadIdx.x;
    if (i < SS * SS) {
        int p = i / SS, s = i - p * SS;
        attG[s * 52 + p] = att[i];
    }
}

// ---------------- kernel 1: hvp[kh][21128][20] = emb[:, kh-half] @ W-half ----------------
// (r12 version, unchanged)
__global__ __launch_bounds__(512) void k_vocab(const float* __restrict__ emb,
                                               const float* __restrict__ Wconv,
                                               const float* __restrict__ Wcross,
                                               float* __restrict__ hvp) {
    __shared__ float tile[8][64][21];
    const int wv = threadIdx.x >> 6, lane = threadIdx.x & 63;
    const int rowbase = blockIdx.x * 64;
    const int rsub = lane >> 2, m = lane & 3;

    const int d0w = blockIdx.y * 384 + __builtin_amdgcn_readfirstlane(wv * 48);

    float4 v[12];
#pragma unroll
    for (int ch = 0; ch < 3; ++ch) {
#pragma unroll
        for (int it = 0; it < 4; ++it) {
            int row = it * 16 + rsub;
            long r = rowbase + row;
            if (r >= VOCAB) r = VOCAB - 1;
            v[ch * 4 + it] = *(const float4*)(emb + r * DD + d0w + ch * 16 + m * 4);
        }
    }

    float acc[20];
#pragma unroll
    for (int c = 0; c < 20; c++) acc[c] = 0.f;

#pragma unroll
    for (int ch = 0; ch < 3; ++ch) {
        const int d0 = d0w + ch * 16;
#pragma unroll
        for (int it = 0; it < 4; ++it) {
            const int row = it * 16 + rsub;
            const float4 w = v[ch * 4 + it];
            tile[wv][row][m * 4 + 0] = w.x;
            tile[wv][row][m * 4 + 1] = w.y;
            tile[wv][row][m * 4 + 2] = w.z;
            tile[wv][row][m * 4 + 3] = w.w;
        }
#pragma unroll
        for (int d = 0; d < 16; ++d) {
            float e = tile[wv][lane][d];
            const float* wc = Wconv + (d0 + d) * 10;
            const float* wx = Wcross + (d0 + d) * 10;
#pragma unroll
            for (int c = 0; c < 10; c++) {
                acc[c] = fmaf(e, wc[c], acc[c]);
                acc[10 + c] = fmaf(e, wx[c], acc[10 + c]);
            }
        }
    }

    __syncthreads();
    float* pp = &tile[0][0][0];
#pragma unroll
    for (int c = 0; c < 20; c++) pp[wv * 1280 + lane * 20 + c] = acc[c];
    __syncthreads();
    float* outp = hvp + (long)blockIdx.y * V20;
    for (int i = threadIdx.x; i < 1280; i += 512) {
        int row = i / 20;
        long r = rowbase + row;
        if (r < VOCAB) {
            float s = 0.f;
#pragma unroll
            for (int w = 0; w < 8; ++w) s += pp[w * 1280 + i];
            outp[r * 20 + (i - row * 20)] = s;
        }
    }
}

// ---------------- kernel 2a: GCN aggregate -> P cols 0-9 ----------------
// 768 blocks x 4 waves, one graph per wave (r15 dataflow minus cross-att).
// Gather is per-lane own-row (lane p loads its own token's conv features).
__global__ __launch_bounds__(256) void k_agg(const int* __restrict__ ctok,
                                             const int* __restrict__ cadj,
                                             const int* __restrict__ rtok,
                                             const int* __restrict__ radj,
                                             const float* __restrict__ hvp,
                                             const float* __restrict__ convb,
                                             float* __restrict__ P) {
    __shared__ float hcv[4][SS][12];    // 9600 B
    __shared__ float aggL[4][SS][11];   // 8800 B
    __shared__ int dgS[4][64];          // 1024 B  -> 19424 B
    const int tid = threadIdx.x, wv = tid >> 6, lane = tid & 63;
    const int G = blockIdx.x * 4 + wv;

    const int* tb;
    const int* ab;
    if (G < NG) { tb = ctok + (long)G * SS; ab = cadj + (long)G * 2 * EE; }
    else        { int b = G - NG; tb = rtok + (long)b * SS; ab = radj + (long)b * 2 * EE; }

    const int e1s = ab[lane], e2s = ab[lane + 64];
    const int e1d = ab[EE + lane], e2d = ab[EE + lane + 64];

    const int p = lane;
    const int pc = (p < SS) ? p : (SS - 1);
    const long t = tb[pc];
    const float4* hv4 = (const float4*)hvp;

    // own-row conv features (cols 0-9), sum of the two K-half partials
    const float4 a0 = hv4[t * 5 + 0], b0 = hv4[(long)(VOCAB * 5) + t * 5 + 0];
    const float4 a1 = hv4[t * 5 + 1], b1 = hv4[(long)(VOCAB * 5) + t * 5 + 1];
    const float4 a2 = hv4[t * 5 + 2], b2 = hv4[(long)(VOCAB * 5) + t * 5 + 2];
    float rowv[CC];
    rowv[0] = a0.x + b0.x; rowv[1] = a0.y + b0.y; rowv[2] = a0.z + b0.z; rowv[3] = a0.w + b0.w;
    rowv[4] = a1.x + b1.x; rowv[5] = a1.y + b1.y; rowv[6] = a1.z + b1.z; rowv[7] = a1.w + b1.w;
    rowv[8] = a2.x + b2.x; rowv[9] = a2.y + b2.y;

    dgS[wv][lane] = 0;
    atomicAdd(&dgS[wv][e1d], 1);
    atomicAdd(&dgS[wv][e2d], 1);

    if (p < SS) {
        *(float4*)&hcv[wv][p][0] = make_float4(rowv[0], rowv[1], rowv[2], rowv[3]);
        *(float4*)&hcv[wv][p][4] = make_float4(rowv[4], rowv[5], rowv[6], rowv[7]);
        *(float2*)&hcv[wv][p][8] = make_float2(rowv[8], rowv[9]);
    }

    float dv = 0.f;
    if (lane < SS) dv = rsqrtf((float)(dgS[wv][lane] + 1));   // +1 self loop

    float* aggW = &aggL[wv][0][0];
    for (int i = lane; i < SS * 11; i += 64) aggW[i] = 0.f;
    const float n1 = __shfl(dv, e1s) * __shfl(dv, e1d);       // full wave: convergent
    const float n2 = __shfl(dv, e2s) * __shfl(dv, e2d);
#pragma unroll
    for (int c = 0; c < CC; c++) atomicAdd(&aggW[e1d * 11 + c], hcv[wv][e1s][c] * n1);
#pragma unroll
    for (int c = 0; c < CC; c++) atomicAdd(&aggW[e2d * 11 + c], hcv[wv][e2s][c] * n2);

    if (p < SS) {
        const float dp2 = dv * dv;
        float g0[CC];
#pragma unroll
        for (int c = 0; c < CC; c++) g0[c] = aggW[p * 11 + c] + rowv[c] * dp2 + convb[c];
        float* o = P + (long)G * 1000 + p * 20;
        *(float4*)(o + 0) = make_float4(g0[0], g0[1], g0[2], g0[3]);
        *(float4*)(o + 4) = make_float4(g0[4], g0[5], g0[6], g0[7]);
        *(float2*)(o + 8) = make_float2(g0[8], g0[9]);
    }
}

// ---------------- kernel 2b: cross-attention -> P cols 10-19 ----------------
// One wave per (graph, c-pair): 15360 waves = 60/CU. Zero LDS, zero barriers.
// lane = node p; each wave computes 2 of the 10 cross columns.
__global__ __launch_bounds__(256) void k_cross(const int* __restrict__ ctok,
                                               const int* __restrict__ rtok,
                                               const float* __restrict__ hvp,
                                               const float* __restrict__ attG,  // [50][52]
                                               float* __restrict__ P) {
    const int tid = threadIdx.x, wv = tid >> 6, lane = tid & 63;
    const int wid = blockIdx.x * 4 + wv;        // 0..15359
    const int g = wid / 5, cpair = wid - g * 5; // wave-uniform
    const int c0 = 10 + 2 * cpair;

    const int* tb = (g < NG) ? (ctok + (long)g * SS) : (rtok + (long)(g - NG) * SS);
    const int pc = (lane < SS) ? lane : (SS - 1);
    const long t = tb[pc];

    // own cross-feature pair (convergent, clamped)
    const float2 xa = *(const float2*)(hvp + t * 20 + c0);
    const float2 xb = *(const float2*)(hvp + (long)V20 + t * 20 + c0);
    const float x0 = xa.x + xb.x;
    const float x1 = xa.y + xb.y;

    float ax0 = 0.f, ax1 = 0.f;
#pragma unroll 10
    for (int s = 0; s < SS; ++s) {
        const float a = attG[s * 52 + pc];      // coalesced across lanes, L1-broadcast-hot
        const float v0 = __uint_as_float(__builtin_amdgcn_readlane(__float_as_uint(x0), s));
        const float v1 = __uint_as_float(__builtin_amdgcn_readlane(__float_as_uint(x1), s));
        ax0 = fmaf(a, v0, ax0);
        ax1 = fmaf(a, v1, ax1);
    }
    if (lane < SS)
        *(float2*)(P + (long)g * 1000 + lane * 20 + c0) = make_float2(ax0, ax1);
}

// ---------------- kernel 3: mpm x10 + final FFN fused (r15 verified, unchanged) ----------------
__global__ __launch_bounds__(640) void k_mpmf(const float* __restrict__ P,
                                              const float* __restrict__ assign,
                                              const float* __restrict__ W1, const float* __restrict__ b1,
                                              const float* __restrict__ W2, const float* __restrict__ b2,
                                              const float* __restrict__ fW1, const float* __restrict__ fb1,
                                              const float* __restrict__ fW2, const float* __restrict__ fb2,
                                              float* __restrict__ out) {
    __shared__ float W2T[20][21];
    __shared__ float asgL[SS][11];
    __shared__ float h1L[10][SS][20];
    __shared__ float guS[TT][20];
    __shared__ float grS[TT][20];
    __shared__ float fsum[256];
    const int tid = threadIdx.x, wv = tid >> 6, lane = tid & 63;
    const int b = blockIdx.x;
    const int t = wv >> 1, which = wv & 1;
    const int g = b * TT + t;

    for (int i = tid; i < 400; i += 640) W2T[i % 20][i / 20] = W2[i];
    for (int i = tid; i < SS * CC; i += 640) asgL[i / CC][i % CC] = assign[i];
    __syncthreads();   // B0

    const float* Pc = P + (long)g * 1000;
    const float* Pr = P + (long)(NG + b) * 1000;
    const float* selfP = which ? Pr : Pc;
    const float* croP  = which ? Pc : Pr;

    const int p = lane;
    float self[CC], cro[CC];
    if (p < SS) {
        const float4* s4 = (const float4*)(selfP + p * 20);
        const float4 a0 = s4[0], a1 = s4[1], a2 = s4[2];
        self[0] = a0.x; self[1] = a0.y; self[2] = a0.z; self[3] = a0.w;
        self[4] = a1.x; self[5] = a1.y; self[6] = a1.z; self[7] = a1.w;
        self[8] = a2.x; self[9] = a2.y;
        const float4* c4 = (const float4*)(croP + p * 20);
        const float4 b0 = c4[2], b1q = c4[3], b2q = c4[4];
        cro[0] = b0.z; cro[1] = b0.w;
        cro[2] = b1q.x; cro[3] = b1q.y; cro[4] = b1q.z; cro[5] = b1q.w;
        cro[6] = b2q.x; cro[7] = b2q.y; cro[8] = b2q.z; cro[9] = b2q.w;
    }

    const int j = lane % 20;
    const int grp = lane / 20;
    float w2r[20];
#pragma unroll
    for (int k = 0; k < 20; k++) w2r[k] = W2T[j][k];

    if (p < SS) {
        float num = 0.f, na = 0.f, nc2 = 0.f;
#pragma unroll
        for (int c = 0; c < CC; c++) {
            float av = asgL[p][c];
            float a = av * self[c];
            float cx = av * cro[c];
            num = fmaf(a, cx, num);
            na = fmaf(a, a, na);
            nc2 = fmaf(cx, cx, nc2);
        }
        float cosv = num / fmaxf(sqrtf(na) * sqrtf(nc2), 1e-8f);
        float h1[20];
#pragma unroll
        for (int q = 0; q < 20; q++) h1[q] = fmaf(cosv, W1[q], b1[q]);
#pragma unroll
        for (int k = 0; k < CC; k++) {
            float sv = self[k];
#pragma unroll
            for (int q = 0; q < 20; q++) h1[q] = fmaf(sv, W1[(k + 1) * 20 + q], h1[q]);
        }
        float4* hw = (float4*)&h1L[wv][p][0];
        hw[0] = make_float4(fmaxf(h1[0], 0.f), fmaxf(h1[1], 0.f), fmaxf(h1[2], 0.f), fmaxf(h1[3], 0.f));
        hw[1] = make_float4(fmaxf(h1[4], 0.f), fmaxf(h1[5], 0.f), fmaxf(h1[6], 0.f), fmaxf(h1[7], 0.f));
        hw[2] = make_float4(fmaxf(h1[8], 0.f), fmaxf(h1[9], 0.f), fmaxf(h1[10], 0.f), fmaxf(h1[11], 0.f));
        hw[3] = make_float4(fmaxf(h1[12], 0.f), fmaxf(h1[13], 0.f), fmaxf(h1[14], 0.f), fmaxf(h1[15], 0.f));
        hw[4] = make_float4(fmaxf(h1[16], 0.f), fmaxf(h1[17], 0.f), fmaxf(h1[18], 0.f), fmaxf(h1[19], 0.f));
    }
    // same-wave ds_write -> ds_read: in-order DS pipe

    float part = -1e30f;
    if (grp < 3) {
        const int s0 = grp * 17;
        const int s1 = (grp == 2) ? SS : (s0 + 17);
        for (int s = s0; s < s1; ++s) {
            const float* hr = &h1L[wv][s][0];
            float tt = 0.f;
#pragma unroll
            for (int k = 0; k < 20; k++) tt = fmaf(hr[k], w2r[k], tt);
            part = fmaxf(part, tt);
        }
    }
    const float a0 = __shfl(part, j);
    const float a1 = __shfl(part, j + 20);
    const float a2 = __shfl(part, j + 40);
    if (lane < 20) {
        float h2 = fmaxf(fmaxf(a0, a1), a2) + b2[lane];
        (which ? grS[t] : guS[t])[lane] = h2;
    }
    __syncthreads();   // B1

    float term = 0.f;
    if (tid < 200) {
        const int tt = tid / 40, jj = tid - tt * 40;
        float hvv = fb1[jj];
#pragma unroll
        for (int k = 0; k < 20; k++) {
            float u = guS[tt][k], r = grS[tt][k];
            hvv = fmaf(u, fW1[k * 40 + jj], hvv);
            hvv = fmaf(r, fW1[(20 + k) * 40 + jj], hvv);
            hvv = fmaf(u * r, fW1[(40 + k) * 40 + jj], hvv);
            hvv = fmaf(fabsf(u - r), fW1[(60 + k) * 40 + jj], hvv);
        }
        term = fmaxf(hvv, 0.f) * fW2[jj];
    }
    if (tid < 256) fsum[tid] = term;
    __syncthreads();   // B2
    if (wv == 0) {
        float s = fsum[lane] + fsum[lane + 64] + fsum[lane + 128] + fsum[lane + 192];
#pragma unroll
        for (int o = 32; o; o >>= 1) s += __shfl_xor(s, o);
        if (lane == 0) out[b] = 1.f / (1.f + expf(-(s + (float)TT * fb2[0])));
    }
}

extern "C" void kernel_launch(void* const* d_in, const int* in_sizes, int n_in,
                              void* d_out, int out_size, void* d_ws, size_t ws_size,
                              hipStream_t stream) {
    (void)in_sizes; (void)n_in; (void)out_size; (void)ws_size;
    const int* ctx_tok = (const int*)d_in[0];
    const int* resp_tok = (const int*)d_in[1];
    const int* ctx_adj = (const int*)d_in[2];
    const int* resp_adj = (const int*)d_in[3];
    const float* emb = (const float*)d_in[4];
    const float* convW = (const float*)d_in[5];
    const float* convb = (const float*)d_in[6];
    const float* crossW = (const float*)d_in[7];
    const float* att = (const float*)d_in[8];
    const float* assign = (const float*)d_in[9];
    const float* mpW1 = (const float*)d_in[10];
    const float* mpb1 = (const float*)d_in[11];
    const float* mpW2 = (const float*)d_in[12];
    const float* mpb2 = (const float*)d_in[13];
    const float* fW1 = (const float*)d_in[14];
    const float* fb1 = (const float*)d_in[15];
    const float* fW2 = (const float*)d_in[16];
    const float* fb2 = (const float*)d_in[17];

    float* ws = (float*)d_ws;
    float* hvp = ws;                       // [2][VOCAB][20]   = 845,120 floats
    float* P = hvp + 2 * V20;              // [3072][50][20]   = 3,072,000
    float* attG = P + (long)NALL * 1000;   // [50][52]         = 2,600
    float* outf = (float*)d_out;

    hipLaunchKernelGGL(k_prep, dim3(40), dim3(64), 0, stream, att, attG);
    hipLaunchKernelGGL(k_vocab, dim3((VOCAB + 63) / 64, 2), dim3(512), 0, stream,
                       emb, convW, crossW, hvp);
    hipLaunchKernelGGL(k_agg, dim3(NALL / 4), dim3(256), 0, stream,
                       ctx_tok, ctx_adj, resp_tok, resp_adj, hvp, convb, P);
    hipLaunchKernelGGL(k_cross, dim3(NALL * 5 / 4), dim3(256), 0, stream,
                       ctx_tok, resp_tok, hvp, attG, P);
    hipLaunchKernelGGL(k_mpmf, dim3(BB), dim3(640), 0, stream,
                       P, assign, mpW1, mpb1, mpW2, mpb2, fW1, fb1, fW2, fb2, outf);
}

// Round 17
// 74.431 us; speedup vs baseline: 1.1764x; 1.1764x over previous
//
#include <hip/hip_runtime.h>
#include <math.h>

#define VOCAB 21128
#define DD 768
#define SS 50
#define TT 5
#define BB 512
#define EE 128
#define CC 10
#define V20 (VOCAB * 20)
#define NG 2560   // utterance graphs; resp graphs are G in [NG, NG+512)
#define NALL 3072 // NG + BB

// ---------------- kernel 0: attG[s][p] = att[p][s], rows padded to 52 ----------------
__global__ void k_prep(const float* __restrict__ att, float* __restrict__ attG) {
    int i = blockIdx.x * 64 + threadIdx.x;
    if (i < SS * SS) {
        int p = i / SS, s = i - p * SS;
        attG[s * 52 + p] = att[i];
    }
}

// ---------------- kernel 1: hvp[kh][21128][20] = emb[:, kh-half] @ W-half ----------------
// (r12 version, unchanged)
__global__ __launch_bounds__(512) void k_vocab(const float* __restrict__ emb,
                                               const float* __restrict__ Wconv,
                                               const float* __restrict__ Wcross,
                                               float* __restrict__ hvp) {
    __shared__ float tile[8][64][21];
    const int wv = threadIdx.x >> 6, lane = threadIdx.x & 63;
    const int rowbase = blockIdx.x * 64;
    const int rsub = lane >> 2, m = lane & 3;

    const int d0w = blockIdx.y * 384 + __builtin_amdgcn_readfirstlane(wv * 48);

    float4 v[12];
#pragma unroll
    for (int ch = 0; ch < 3; ++ch) {
#pragma unroll
        for (int it = 0; it < 4; ++it) {
            int row = it * 16 + rsub;
            long r = rowbase + row;
            if (r >= VOCAB) r = VOCAB - 1;
            v[ch * 4 + it] = *(const float4*)(emb + r * DD + d0w + ch * 16 + m * 4);
        }
    }

    float acc[20];
#pragma unroll
    for (int c = 0; c < 20; c++) acc[c] = 0.f;

#pragma unroll
    for (int ch = 0; ch < 3; ++ch) {
        const int d0 = d0w + ch * 16;
#pragma unroll
        for (int it = 0; it < 4; ++it) {
            const int row = it * 16 + rsub;
            const float4 w = v[ch * 4 + it];
            tile[wv][row][m * 4 + 0] = w.x;
            tile[wv][row][m * 4 + 1] = w.y;
            tile[wv][row][m * 4 + 2] = w.z;
            tile[wv][row][m * 4 + 3] = w.w;
        }
#pragma unroll
        for (int d = 0; d < 16; ++d) {
            float e = tile[wv][lane][d];
            const float* wc = Wconv + (d0 + d) * 10;
            const float* wx = Wcross + (d0 + d) * 10;
#pragma unroll
            for (int c = 0; c < 10; c++) {
                acc[c] = fmaf(e, wc[c], acc[c]);
                acc[10 + c] = fmaf(e, wx[c], acc[10 + c]);
            }
        }
    }

    __syncthreads();
    float* pp = &tile[0][0][0];
#pragma unroll
    for (int c = 0; c < 20; c++) pp[wv * 1280 + lane * 20 + c] = acc[c];
    __syncthreads();
    float* outp = hvp + (long)blockIdx.y * V20;
    for (int i = threadIdx.x; i < 1280; i += 512) {
        int row = i / 20;
        long r = rowbase + row;
        if (r < VOCAB) {
            float s = 0.f;
#pragma unroll
            for (int w = 0; w < 8; ++w) s += pp[w * 1280 + i];
            outp[r * 20 + (i - row * 20)] = s;
        }
    }
}

// ---------------- kernel 2: unified GCN for all 3072 graphs -> P[G][50][20] ----------------
// r15 dataflow; CHANGES: (1) hcx LDS deleted -- cross features come from per-lane
// own-row global loads (r16-verified pattern); (2) conv row also own-row load.
// LDS 29 -> 19.4 KB => 8 blocks/CU = 32 waves/CU (was 5/20). Zero barriers.
__global__ __launch_bounds__(256) void k_gcn(const int* __restrict__ ctok,
                                             const int* __restrict__ cadj,
                                             const int* __restrict__ rtok,
                                             const int* __restrict__ radj,
                                             const float* __restrict__ hvp,
                                             const float* __restrict__ convb,
                                             const float* __restrict__ attG,  // [50][52]
                                             float* __restrict__ P) {
    __shared__ float hcv[4][SS][12];    // 9600 B (conv rows, needed for neighbor access)
    __shared__ float aggL[4][SS][11];   // 8800 B
    __shared__ int dgS[4][64];          // 1024 B  -> 19424 B, 8 blocks/CU
    const int tid = threadIdx.x, wv = tid >> 6, lane = tid & 63;
    const int G = blockIdx.x * 4 + wv;

    const int* tb;
    const int* ab;
    if (G < NG) { tb = ctok + (long)G * SS; ab = cadj + (long)G * 2 * EE; }
    else        { int b = G - NG; tb = rtok + (long)b * SS; ab = radj + (long)b * 2 * EE; }

    const int e1s = ab[lane], e2s = ab[lane + 64];
    const int e1d = ab[EE + lane], e2d = ab[EE + lane + 64];

    const int p = lane;
    const int pc = (p < SS) ? p : (SS - 1);
    const long t = tb[pc];
    const float4* hv4 = (const float4*)hvp;

    // own-row features (r16-verified): 5 float4 x 2 K-half partials
    float4 qa[5], qb[5];
#pragma unroll
    for (int qi = 0; qi < 5; ++qi) {
        qa[qi] = hv4[t * 5 + qi];
        qb[qi] = hv4[(long)(VOCAB * 5) + t * 5 + qi];
    }
    float rowv[CC], xo[CC];
    rowv[0] = qa[0].x + qb[0].x; rowv[1] = qa[0].y + qb[0].y;
    rowv[2] = qa[0].z + qb[0].z; rowv[3] = qa[0].w + qb[0].w;
    rowv[4] = qa[1].x + qb[1].x; rowv[5] = qa[1].y + qb[1].y;
    rowv[6] = qa[1].z + qb[1].z; rowv[7] = qa[1].w + qb[1].w;
    rowv[8] = qa[2].x + qb[2].x; rowv[9] = qa[2].y + qb[2].y;
    xo[0] = qa[2].z + qb[2].z; xo[1] = qa[2].w + qb[2].w;
    xo[2] = qa[3].x + qb[3].x; xo[3] = qa[3].y + qb[3].y;
    xo[4] = qa[3].z + qb[3].z; xo[5] = qa[3].w + qb[3].w;
    xo[6] = qa[4].x + qb[4].x; xo[7] = qa[4].y + qb[4].y;
    xo[8] = qa[4].z + qb[4].z; xo[9] = qa[4].w + qb[4].w;

    dgS[wv][lane] = 0;
    atomicAdd(&dgS[wv][e1d], 1);
    atomicAdd(&dgS[wv][e2d], 1);

    if (p < SS) {
        *(float4*)&hcv[wv][p][0] = make_float4(rowv[0], rowv[1], rowv[2], rowv[3]);
        *(float4*)&hcv[wv][p][4] = make_float4(rowv[4], rowv[5], rowv[6], rowv[7]);
        *(float2*)&hcv[wv][p][8] = make_float2(rowv[8], rowv[9]);
    }

    float dv = 0.f;
    if (lane < SS) dv = rsqrtf((float)(dgS[wv][lane] + 1));   // +1 self loop

    float* aggW = &aggL[wv][0][0];
    for (int i = lane; i < SS * 11; i += 64) aggW[i] = 0.f;
    const float n1 = __shfl(dv, e1s) * __shfl(dv, e1d);       // full wave: convergent
    const float n2 = __shfl(dv, e2s) * __shfl(dv, e2d);
#pragma unroll
    for (int c = 0; c < CC; c++) atomicAdd(&aggW[e1d * 11 + c], hcv[wv][e1s][c] * n1);
#pragma unroll
    for (int c = 0; c < CC; c++) atomicAdd(&aggW[e2d * 11 + c], hcv[wv][e2s][c] * n2);

    if (p < SS) {
        float gcn[CC];
        const float dp2 = dv * dv;
#pragma unroll
        for (int c = 0; c < CC; c++) gcn[c] = aggW[p * 11 + c] + rowv[c] * dp2 + convb[c];

        float ax[CC];
#pragma unroll
        for (int c = 0; c < CC; c++) ax[c] = 0.f;
#pragma unroll 5
        for (int s = 0; s < SS; ++s) {
            const float a = attG[s * 52 + p];         // coalesced in p; L1-hot (10 KB)
#pragma unroll
            for (int c = 0; c < CC; c++) {
                const float xs = __uint_as_float(
                    __builtin_amdgcn_readlane(__float_as_uint(xo[c]), s));  // exec-independent
                ax[c] = fmaf(a, xs, ax[c]);
            }
        }
        float4* o4 = (float4*)(P + (long)G * 1000 + p * 20);
        o4[0] = make_float4(gcn[0], gcn[1], gcn[2], gcn[3]);
        o4[1] = make_float4(gcn[4], gcn[5], gcn[6], gcn[7]);
        o4[2] = make_float4(gcn[8], gcn[9], ax[0], ax[1]);
        o4[3] = make_float4(ax[2], ax[3], ax[4], ax[5]);
        o4[4] = make_float4(ax[6], ax[7], ax[8], ax[9]);
    }
}

// ---------------- kernel 3: mpm x10 + final FFN fused (r15 verified, unchanged) ----------------
__global__ __launch_bounds__(640) void k_mpmf(const float* __restrict__ P,
                                              const float* __restrict__ assign,
                                              const float* __restrict__ W1, const float* __restrict__ b1,
                                              const float* __restrict__ W2, const float* __restrict__ b2,
                                              const float* __restrict__ fW1, const float* __restrict__ fb1,
                                              const float* __restrict__ fW2, const float* __restrict__ fb2,
                                              float* __restrict__ out) {
    __shared__ float W2T[20][21];
    __shared__ float asgL[SS][11];
    __shared__ float h1L[10][SS][20];
    __shared__ float guS[TT][20];
    __shared__ float grS[TT][20];
    __shared__ float fsum[256];
    const int tid = threadIdx.x, wv = tid >> 6, lane = tid & 63;
    const int b = blockIdx.x;
    const int t = wv >> 1, which = wv & 1;
    const int g = b * TT + t;

    for (int i = tid; i < 400; i += 640) W2T[i % 20][i / 20] = W2[i];
    for (int i = tid; i < SS * CC; i += 640) asgL[i / CC][i % CC] = assign[i];
    __syncthreads();   // B0

    const float* Pc = P + (long)g * 1000;
    const float* Pr = P + (long)(NG + b) * 1000;
    const float* selfP = which ? Pr : Pc;
    const float* croP  = which ? Pc : Pr;

    const int p = lane;
    float self[CC], cro[CC];
    if (p < SS) {
        const float4* s4 = (const float4*)(selfP + p * 20);
        const float4 a0 = s4[0], a1 = s4[1], a2 = s4[2];
        self[0] = a0.x; self[1] = a0.y; self[2] = a0.z; self[3] = a0.w;
        self[4] = a1.x; self[5] = a1.y; self[6] = a1.z; self[7] = a1.w;
        self[8] = a2.x; self[9] = a2.y;
        const float4* c4 = (const float4*)(croP + p * 20);
        const float4 b0 = c4[2], b1q = c4[3], b2q = c4[4];
        cro[0] = b0.z; cro[1] = b0.w;
        cro[2] = b1q.x; cro[3] = b1q.y; cro[4] = b1q.z; cro[5] = b1q.w;
        cro[6] = b2q.x; cro[7] = b2q.y; cro[8] = b2q.z; cro[9] = b2q.w;
    }

    const int j = lane % 20;
    const int grp = lane / 20;
    float w2r[20];
#pragma unroll
    for (int k = 0; k < 20; k++) w2r[k] = W2T[j][k];

    if (p < SS) {
        float num = 0.f, na = 0.f, nc2 = 0.f;
#pragma unroll
        for (int c = 0; c < CC; c++) {
            float av = asgL[p][c];
            float a = av * self[c];
            float cx = av * cro[c];
            num = fmaf(a, cx, num);
            na = fmaf(a, a, na);
            nc2 = fmaf(cx, cx, nc2);
        }
        float cosv = num / fmaxf(sqrtf(na) * sqrtf(nc2), 1e-8f);
        float h1[20];
#pragma unroll
        for (int q = 0; q < 20; q++) h1[q] = fmaf(cosv, W1[q], b1[q]);
#pragma unroll
        for (int k = 0; k < CC; k++) {
            float sv = self[k];
#pragma unroll
            for (int q = 0; q < 20; q++) h1[q] = fmaf(sv, W1[(k + 1) * 20 + q], h1[q]);
        }
        float4* hw = (float4*)&h1L[wv][p][0];
        hw[0] = make_float4(fmaxf(h1[0], 0.f), fmaxf(h1[1], 0.f), fmaxf(h1[2], 0.f), fmaxf(h1[3], 0.f));
        hw[1] = make_float4(fmaxf(h1[4], 0.f), fmaxf(h1[5], 0.f), fmaxf(h1[6], 0.f), fmaxf(h1[7], 0.f));
        hw[2] = make_float4(fmaxf(h1[8], 0.f), fmaxf(h1[9], 0.f), fmaxf(h1[10], 0.f), fmaxf(h1[11], 0.f));
        hw[3] = make_float4(fmaxf(h1[12], 0.f), fmaxf(h1[13], 0.f), fmaxf(h1[14], 0.f), fmaxf(h1[15], 0.f));
        hw[4] = make_float4(fmaxf(h1[16], 0.f), fmaxf(h1[17], 0.f), fmaxf(h1[18], 0.f), fmaxf(h1[19], 0.f));
    }
    // same-wave ds_write -> ds_read: in-order DS pipe

    float part = -1e30f;
    if (grp < 3) {
        const int s0 = grp * 17;
        const int s1 = (grp == 2) ? SS : (s0 + 17);
        for (int s = s0; s < s1; ++s) {
            const float* hr = &h1L[wv][s][0];
            float tt = 0.f;
#pragma unroll
            for (int k = 0; k < 20; k++) tt = fmaf(hr[k], w2r[k], tt);
            part = fmaxf(part, tt);
        }
    }
    const float a0 = __shfl(part, j);
    const float a1 = __shfl(part, j + 20);
    const float a2 = __shfl(part, j + 40);
    if (lane < 20) {
        float h2 = fmaxf(fmaxf(a0, a1), a2) + b2[lane];
        (which ? grS[t] : guS[t])[lane] = h2;
    }
    __syncthreads();   // B1

    float term = 0.f;
    if (tid < 200) {
        const int tt = tid / 40, jj = tid - tt * 40;
        float hvv = fb1[jj];
#pragma unroll
        for (int k = 0; k < 20; k++) {
            float u = guS[tt][k], r = grS[tt][k];
            hvv = fmaf(u, fW1[k * 40 + jj], hvv);
            hvv = fmaf(r, fW1[(20 + k) * 40 + jj], hvv);
            hvv = fmaf(u * r, fW1[(40 + k) * 40 + jj], hvv);
            hvv = fmaf(fabsf(u - r), fW1[(60 + k) * 40 + jj], hvv);
        }
        term = fmaxf(hvv, 0.f) * fW2[jj];
    }
    if (tid < 256) fsum[tid] = term;
    __syncthreads();   // B2
    if (wv == 0) {
        float s = fsum[lane] + fsum[lane + 64] + fsum[lane + 128] + fsum[lane + 192];
#pragma unroll
        for (int o = 32; o; o >>= 1) s += __shfl_xor(s, o);
        if (lane == 0) out[b] = 1.f / (1.f + expf(-(s + (float)TT * fb2[0])));
    }
}

extern "C" void kernel_launch(void* const* d_in, const int* in_sizes, int n_in,
                              void* d_out, int out_size, void* d_ws, size_t ws_size,
                              hipStream_t stream) {
    (void)in_sizes; (void)n_in; (void)out_size; (void)ws_size;
    const int* ctx_tok = (const int*)d_in[0];
    const int* resp_tok = (const int*)d_in[1];
    const int* ctx_adj = (const int*)d_in[2];
    const int* resp_adj = (const int*)d_in[3];
    const float* emb = (const float*)d_in[4];
    const float* convW = (const float*)d_in[5];
    const float* convb = (const float*)d_in[6];
    const float* crossW = (const float*)d_in[7];
    const float* att = (const float*)d_in[8];
    const float* assign = (const float*)d_in[9];
    const float* mpW1 = (const float*)d_in[10];
    const float* mpb1 = (const float*)d_in[11];
    const float* mpW2 = (const float*)d_in[12];
    const float* mpb2 = (const float*)d_in[13];
    const float* fW1 = (const float*)d_in[14];
    const float* fb1 = (const float*)d_in[15];
    const float* fW2 = (const float*)d_in[16];
    const float* fb2 = (const float*)d_in[17];

    float* ws = (float*)d_ws;
    float* hvp = ws;                       // [2][VOCAB][20]   = 845,120 floats
    float* P = hvp + 2 * V20;              // [3072][50][20]   = 3,072,000
    float* attG = P + (long)NALL * 1000;   // [50][52]         = 2,600
    float* outf = (float*)d_out;

    hipLaunchKernelGGL(k_prep, dim3(40), dim3(64), 0, stream, att, attG);
    hipLaunchKernelGGL(k_vocab, dim3((VOCAB + 63) / 64, 2), dim3(512), 0, stream,
                       emb, convW, crossW, hvp);
    hipLaunchKernelGGL(k_gcn, dim3(NALL / 4), dim3(256), 0, stream,
                       ctx_tok, ctx_adj, resp_tok, resp_adj, hvp, convb, attG, P);
    hipLaunchKernelGGL(k_mpmf, dim3(BB), dim3(640), 0, stream,
                       P, assign, mpW1, mpb1, mpW2, mpb2, fW1, fb1, fW2, fb2, outf);
}

// Round 18
// 69.542 us; speedup vs baseline: 1.2591x; 1.0703x over previous
//
#include <hip/hip_runtime.h>
#include <math.h>

#define VOCAB 21128
#define DD 768
#define SS 50
#define TT 5
#define BB 512
#define EE 128
#define CC 10
#define V20 (VOCAB * 20)
#define NG 2560   // utterance graphs; resp graphs are G in [NG, NG+512)
#define NALL 3072 // NG + BB

// ---------------- kernel 1: hvp[kh][21128][20] = emb[:, kh-half] @ W-half ----------------
// r18: k_prep folded in -- grid (332,2); the over-range tail block (x=331,y=0) does the
// att transpose (attG[s*52+p] = att[p*50+s]) instead of row work. Otherwise r12 version.
__global__ __launch_bounds__(512) void k_vocab(const float* __restrict__ emb,
                                               const float* __restrict__ Wconv,
                                               const float* __restrict__ Wcross,
                                               const float* __restrict__ att,
                                               float* __restrict__ attG,
                                               float* __restrict__ hvp) {
    __shared__ float tile[8][64][21];
    const int wv = threadIdx.x >> 6, lane = threadIdx.x & 63;
    const int rowbase = blockIdx.x * 64;

    if (rowbase >= VOCAB) {               // tail block: do the att transpose (y==0 only)
        if (blockIdx.y == 0) {
            for (int i = threadIdx.x; i < SS * SS; i += 512) {
                int p = i / SS, s = i - p * SS;
                attG[s * 52 + p] = att[i];
            }
        }
        return;
    }

    const int rsub = lane >> 2, m = lane & 3;
    const int d0w = blockIdx.y * 384 + __builtin_amdgcn_readfirstlane(wv * 48);

    float4 v[12];
#pragma unroll
    for (int ch = 0; ch < 3; ++ch) {
#pragma unroll
        for (int it = 0; it < 4; ++it) {
            int row = it * 16 + rsub;
            long r = rowbase + row;
            if (r >= VOCAB) r = VOCAB - 1;
            v[ch * 4 + it] = *(const float4*)(emb + r * DD + d0w + ch * 16 + m * 4);
        }
    }

    float acc[20];
#pragma unroll
    for (int c = 0; c < 20; c++) acc[c] = 0.f;

#pragma unroll
    for (int ch = 0; ch < 3; ++ch) {
        const int d0 = d0w + ch * 16;
#pragma unroll
        for (int it = 0; it < 4; ++it) {
            const int row = it * 16 + rsub;
            const float4 w = v[ch * 4 + it];
            tile[wv][row][m * 4 + 0] = w.x;
            tile[wv][row][m * 4 + 1] = w.y;
            tile[wv][row][m * 4 + 2] = w.z;
            tile[wv][row][m * 4 + 3] = w.w;
        }
#pragma unroll
        for (int d = 0; d < 16; ++d) {
            float e = tile[wv][lane][d];
            const float* wc = Wconv + (d0 + d) * 10;
            const float* wx = Wcross + (d0 + d) * 10;
#pragma unroll
            for (int c = 0; c < 10; c++) {
                acc[c] = fmaf(e, wc[c], acc[c]);
                acc[10 + c] = fmaf(e, wx[c], acc[10 + c]);
            }
        }
    }

    __syncthreads();
    float* pp = &tile[0][0][0];
#pragma unroll
    for (int c = 0; c < 20; c++) pp[wv * 1280 + lane * 20 + c] = acc[c];
    __syncthreads();
    float* outp = hvp + (long)blockIdx.y * V20;
    for (int i = threadIdx.x; i < 1280; i += 512) {
        int row = i / 20;
        long r = rowbase + row;
        if (r < VOCAB) {
            float s = 0.f;
#pragma unroll
            for (int w = 0; w < 8; ++w) s += pp[w * 1280 + i];
            outp[r * 20 + (i - row * 20)] = s;
        }
    }
}

// ---------------- kernel 2: unified GCN for all 3072 graphs -> P[G][50][20] ----------------
// (r17 version, unchanged: own-row gather, no hcx, 19.4 KB LDS -> 32 waves/CU, 0 barriers)
__global__ __launch_bounds__(256) void k_gcn(const int* __restrict__ ctok,
                                             const int* __restrict__ cadj,
                                             const int* __restrict__ rtok,
                                             const int* __restrict__ radj,
                                             const float* __restrict__ hvp,
                                             const float* __restrict__ convb,
                                             const float* __restrict__ attG,  // [50][52]
                                             float* __restrict__ P) {
    __shared__ float hcv[4][SS][12];
    __shared__ float aggL[4][SS][11];
    __shared__ int dgS[4][64];
    const int tid = threadIdx.x, wv = tid >> 6, lane = tid & 63;
    const int G = blockIdx.x * 4 + wv;

    const int* tb;
    const int* ab;
    if (G < NG) { tb = ctok + (long)G * SS; ab = cadj + (long)G * 2 * EE; }
    else        { int b = G - NG; tb = rtok + (long)b * SS; ab = radj + (long)b * 2 * EE; }

    const int e1s = ab[lane], e2s = ab[lane + 64];
    const int e1d = ab[EE + lane], e2d = ab[EE + lane + 64];

    const int p = lane;
    const int pc = (p < SS) ? p : (SS - 1);
    const long t = tb[pc];
    const float4* hv4 = (const float4*)hvp;

    float4 qa[5], qb[5];
#pragma unroll
    for (int qi = 0; qi < 5; ++qi) {
        qa[qi] = hv4[t * 5 + qi];
        qb[qi] = hv4[(long)(VOCAB * 5) + t * 5 + qi];
    }
    float rowv[CC], xo[CC];
    rowv[0] = qa[0].x + qb[0].x; rowv[1] = qa[0].y + qb[0].y;
    rowv[2] = qa[0].z + qb[0].z; rowv[3] = qa[0].w + qb[0].w;
    rowv[4] = qa[1].x + qb[1].x; rowv[5] = qa[1].y + qb[1].y;
    rowv[6] = qa[1].z + qb[1].z; rowv[7] = qa[1].w + qb[1].w;
    rowv[8] = qa[2].x + qb[2].x; rowv[9] = qa[2].y + qb[2].y;
    xo[0] = qa[2].z + qb[2].z; xo[1] = qa[2].w + qb[2].w;
    xo[2] = qa[3].x + qb[3].x; xo[3] = qa[3].y + qb[3].y;
    xo[4] = qa[3].z + qb[3].z; xo[5] = qa[3].w + qb[3].w;
    xo[6] = qa[4].x + qb[4].x; xo[7] = qa[4].y + qb[4].y;
    xo[8] = qa[4].z + qb[4].z; xo[9] = qa[4].w + qb[4].w;

    dgS[wv][lane] = 0;
    atomicAdd(&dgS[wv][e1d], 1);
    atomicAdd(&dgS[wv][e2d], 1);

    if (p < SS) {
        *(float4*)&hcv[wv][p][0] = make_float4(rowv[0], rowv[1], rowv[2], rowv[3]);
        *(float4*)&hcv[wv][p][4] = make_float4(rowv[4], rowv[5], rowv[6], rowv[7]);
        *(float2*)&hcv[wv][p][8] = make_float2(rowv[8], rowv[9]);
    }

    float dv = 0.f;
    if (lane < SS) dv = rsqrtf((float)(dgS[wv][lane] + 1));   // +1 self loop

    float* aggW = &aggL[wv][0][0];
    for (int i = lane; i < SS * 11; i += 64) aggW[i] = 0.f;
    const float n1 = __shfl(dv, e1s) * __shfl(dv, e1d);       // full wave: convergent
    const float n2 = __shfl(dv, e2s) * __shfl(dv, e2d);
#pragma unroll
    for (int c = 0; c < CC; c++) atomicAdd(&aggW[e1d * 11 + c], hcv[wv][e1s][c] * n1);
#pragma unroll
    for (int c = 0; c < CC; c++) atomicAdd(&aggW[e2d * 11 + c], hcv[wv][e2s][c] * n2);

    if (p < SS) {
        float gcn[CC];
        const float dp2 = dv * dv;
#pragma unroll
        for (int c = 0; c < CC; c++) gcn[c] = aggW[p * 11 + c] + rowv[c] * dp2 + convb[c];

        float ax[CC];
#pragma unroll
        for (int c = 0; c < CC; c++) ax[c] = 0.f;
#pragma unroll 5
        for (int s = 0; s < SS; ++s) {
            const float a = attG[s * 52 + p];         // coalesced in p; L1-hot (10 KB)
#pragma unroll
            for (int c = 0; c < CC; c++) {
                const float xs = __uint_as_float(
                    __builtin_amdgcn_readlane(__float_as_uint(xo[c]), s));  // exec-independent
                ax[c] = fmaf(a, xs, ax[c]);
            }
        }
        float4* o4 = (float4*)(P + (long)G * 1000 + p * 20);
        o4[0] = make_float4(gcn[0], gcn[1], gcn[2], gcn[3]);
        o4[1] = make_float4(gcn[4], gcn[5], gcn[6], gcn[7]);
        o4[2] = make_float4(gcn[8], gcn[9], ax[0], ax[1]);
        o4[3] = make_float4(ax[2], ax[3], ax[4], ax[5]);
        o4[4] = make_float4(ax[6], ax[7], ax[8], ax[9]);
    }
}

// ---------------- kernel 3: mpm x10 + final FFN fused (r15 verified, unchanged) ----------------
__global__ __launch_bounds__(640) void k_mpmf(const float* __restrict__ P,
                                              const float* __restrict__ assign,
                                              const float* __restrict__ W1, const float* __restrict__ b1,
                                              const float* __restrict__ W2, const float* __restrict__ b2,
                                              const float* __restrict__ fW1, const float* __restrict__ fb1,
                                              const float* __restrict__ fW2, const float* __restrict__ fb2,
                                              float* __restrict__ out) {
    __shared__ float W2T[20][21];
    __shared__ float asgL[SS][11];
    __shared__ float h1L[10][SS][20];
    __shared__ float guS[TT][20];
    __shared__ float grS[TT][20];
    __shared__ float fsum[256];
    const int tid = threadIdx.x, wv = tid >> 6, lane = tid & 63;
    const int b = blockIdx.x;
    const int t = wv >> 1, which = wv & 1;
    const int g = b * TT + t;

    for (int i = tid; i < 400; i += 640) W2T[i % 20][i / 20] = W2[i];
    for (int i = tid; i < SS * CC; i += 640) asgL[i / CC][i % CC] = assign[i];
    __syncthreads();   // B0

    const float* Pc = P + (long)g * 1000;
    const float* Pr = P + (long)(NG + b) * 1000;
    const float* selfP = which ? Pr : Pc;
    const float* croP  = which ? Pc : Pr;

    const int p = lane;
    float self[CC], cro[CC];
    if (p < SS) {
        const float4* s4 = (const float4*)(selfP + p * 20);
        const float4 a0 = s4[0], a1 = s4[1], a2 = s4[2];
        self[0] = a0.x; self[1] = a0.y; self[2] = a0.z; self[3] = a0.w;
        self[4] = a1.x; self[5] = a1.y; self[6] = a1.z; self[7] = a1.w;
        self[8] = a2.x; self[9] = a2.y;
        const float4* c4 = (const float4*)(croP + p * 20);
        const float4 b0 = c4[2], b1q = c4[3], b2q = c4[4];
        cro[0] = b0.z; cro[1] = b0.w;
        cro[2] = b1q.x; cro[3] = b1q.y; cro[4] = b1q.z; cro[5] = b1q.w;
        cro[6] = b2q.x; cro[7] = b2q.y; cro[8] = b2q.z; cro[9] = b2q.w;
    }

    const int j = lane % 20;
    const int grp = lane / 20;
    float w2r[20];
#pragma unroll
    for (int k = 0; k < 20; k++) w2r[k] = W2T[j][k];

    if (p < SS) {
        float num = 0.f, na = 0.f, nc2 = 0.f;
#pragma unroll
        for (int c = 0; c < CC; c++) {
            float av = asgL[p][c];
            float a = av * self[c];
            float cx = av * cro[c];
            num = fmaf(a, cx, num);
            na = fmaf(a, a, na);
            nc2 = fmaf(cx, cx, nc2);
        }
        float cosv = num / fmaxf(sqrtf(na) * sqrtf(nc2), 1e-8f);
        float h1[20];
#pragma unroll
        for (int q = 0; q < 20; q++) h1[q] = fmaf(cosv, W1[q], b1[q]);
#pragma unroll
        for (int k = 0; k < CC; k++) {
            float sv = self[k];
#pragma unroll
            for (int q = 0; q < 20; q++) h1[q] = fmaf(sv, W1[(k + 1) * 20 + q], h1[q]);
        }
        float4* hw = (float4*)&h1L[wv][p][0];
        hw[0] = make_float4(fmaxf(h1[0], 0.f), fmaxf(h1[1], 0.f), fmaxf(h1[2], 0.f), fmaxf(h1[3], 0.f));
        hw[1] = make_float4(fmaxf(h1[4], 0.f), fmaxf(h1[5], 0.f), fmaxf(h1[6], 0.f), fmaxf(h1[7], 0.f));
        hw[2] = make_float4(fmaxf(h1[8], 0.f), fmaxf(h1[9], 0.f), fmaxf(h1[10], 0.f), fmaxf(h1[11], 0.f));
        hw[3] = make_float4(fmaxf(h1[12], 0.f), fmaxf(h1[13], 0.f), fmaxf(h1[14], 0.f), fmaxf(h1[15], 0.f));
        hw[4] = make_float4(fmaxf(h1[16], 0.f), fmaxf(h1[17], 0.f), fmaxf(h1[18], 0.f), fmaxf(h1[19], 0.f));
    }
    // same-wave ds_write -> ds_read: in-order DS pipe

    float part = -1e30f;
    if (grp < 3) {
        const int s0 = grp * 17;
        const int s1 = (grp == 2) ? SS : (s0 + 17);
        for (int s = s0; s < s1; ++s) {
            const float* hr = &h1L[wv][s][0];
            float tt = 0.f;
#pragma unroll
            for (int k = 0; k < 20; k++) tt = fmaf(hr[k], w2r[k], tt);
            part = fmaxf(part, tt);
        }
    }
    const float a0 = __shfl(part, j);
    const float a1 = __shfl(part, j + 20);
    const float a2 = __shfl(part, j + 40);
    if (lane < 20) {
        float h2 = fmaxf(fmaxf(a0, a1), a2) + b2[lane];
        (which ? grS[t] : guS[t])[lane] = h2;
    }
    __syncthreads();   // B1

    float term = 0.f;
    if (tid < 200) {
        const int tt = tid / 40, jj = tid - tt * 40;
        float hvv = fb1[jj];
#pragma unroll
        for (int k = 0; k < 20; k++) {
            float u = guS[tt][k], r = grS[tt][k];
            hvv = fmaf(u, fW1[k * 40 + jj], hvv);
            hvv = fmaf(r, fW1[(20 + k) * 40 + jj], hvv);
            hvv = fmaf(u * r, fW1[(40 + k) * 40 + jj], hvv);
            hvv = fmaf(fabsf(u - r), fW1[(60 + k) * 40 + jj], hvv);
        }
        term = fmaxf(hvv, 0.f) * fW2[jj];
    }
    if (tid < 256) fsum[tid] = term;
    __syncthreads();   // B2
    if (wv == 0) {
        float s = fsum[lane] + fsum[lane + 64] + fsum[lane + 128] + fsum[lane + 192];
#pragma unroll
        for (int o = 32; o; o >>= 1) s += __shfl_xor(s, o);
        if (lane == 0) out[b] = 1.f / (1.f + expf(-(s + (float)TT * fb2[0])));
    }
}

extern "C" void kernel_launch(void* const* d_in, const int* in_sizes, int n_in,
                              void* d_out, int out_size, void* d_ws, size_t ws_size,
                              hipStream_t stream) {
    (void)in_sizes; (void)n_in; (void)out_size; (void)ws_size;
    const int* ctx_tok = (const int*)d_in[0];
    const int* resp_tok = (const int*)d_in[1];
    const int* ctx_adj = (const int*)d_in[2];
    const int* resp_adj = (const int*)d_in[3];
    const float* emb = (const float*)d_in[4];
    const float* convW = (const float*)d_in[5];
    const float* convb = (const float*)d_in[6];
    const float* crossW = (const float*)d_in[7];
    const float* att = (const float*)d_in[8];
    const float* assign = (const float*)d_in[9];
    const float* mpW1 = (const float*)d_in[10];
    const float* mpb1 = (const float*)d_in[11];
    const float* mpW2 = (const float*)d_in[12];
    const float* mpb2 = (const float*)d_in[13];
    const float* fW1 = (const float*)d_in[14];
    const float* fb1 = (const float*)d_in[15];
    const float* fW2 = (const float*)d_in[16];
    const float* fb2 = (const float*)d_in[17];

    float* ws = (float*)d_ws;
    float* hvp = ws;                       // [2][VOCAB][20]   = 845,120 floats
    float* P = hvp + 2 * V20;              // [3072][50][20]   = 3,072,000
    float* attG = P + (long)NALL * 1000;   // [50][52]         = 2,600
    float* outf = (float*)d_out;

    hipLaunchKernelGGL(k_vocab, dim3((VOCAB + 63) / 64 + 1, 2), dim3(512), 0, stream,
                       emb, convW, crossW, att, attG, hvp);
    hipLaunchKernelGGL(k_gcn, dim3(NALL / 4), dim3(256), 0, stream,
                       ctx_tok, ctx_adj, resp_tok, resp_adj, hvp, convb, attG, P);
    hipLaunchKernelGGL(k_mpmf, dim3(BB), dim3(640), 0, stream,
                       P, assign, mpW1, mpb1, mpW2, mpb2, fW1, fb1, fW2, fb2, outf);
}